// Round 1
// baseline (284.996 us; speedup 1.0000x reference)
//
#include <hip/hip_runtime.h>
#include <stdint.h>

// Two-phase fused causal linear attention (B=4 H=16 T=2048 D=128, fp32 io):
//   out[b,h,i,:] = sum_{j<=i} (q_i . k_j) * v_j
// Phase A (k_state): exclusive prefix states S_pre(c) = sum_{c'<c} K_c'^T V_c'
//   grid 256 = 64 bh x 4 d-slices; states stored bf16 in d_ws, pre-swizzled
//   into MFMA B-fragment layout for phase B.  Needs ws_size >= 32 MiB.
// Phase B (k_out): 1024 fully parallel blocks (bh, chunk):
//   O_c = Q_c @ S_pre(c) + tril(Q_c K_c^T) @ V_c.  One barrier per block,
//   scores computed once (not per D-slice), no scalar LDS column gathers.
#define SEQ    2048
#define DIM    128
#define CHUNK  128
#define NCHUNK 16
#define NBH    64
#define DSLA   4
#define DCA    32           // DIM / DSLA

typedef __attribute__((ext_vector_type(8))) short short8;   // 8 bf16
typedef __attribute__((ext_vector_type(4))) float floatx4;  // MFMA acc

#define MFMA(a, b, c) __builtin_amdgcn_mfma_f32_16x16x32_bf16((a), (b), (c), 0, 0, 0)

__device__ __forceinline__ short f2bf(float f) {
  union { float f; uint32_t u; } x; x.f = f;
  uint32_t r = x.u + 0x7fffu + ((x.u >> 16) & 1u);   // RNE
  return (short)(r >> 16);
}
__device__ __forceinline__ short8 pack8(const float4 a, const float4 b) {
  short8 s;
  s[0] = f2bf(a.x); s[1] = f2bf(a.y); s[2] = f2bf(a.z); s[3] = f2bf(a.w);
  s[4] = f2bf(b.x); s[5] = f2bf(b.y); s[6] = f2bf(b.z); s[7] = f2bf(b.w);
  return s;
}

// ---------------------------------------------------------------------------
// Kernel A: exclusive prefix of S_c = K_c^T V_c  (slice of 32 d-columns).
// Wave w owns d'-tile w (S columns 16w..16w+15), both 16-row d tiles.
// ws record for (bh,c): 16384 shorts; slice dsl at +dsl*4096; within a slice
// thread t = ks*128 + tn_local*64 + lane holds frag bytes t*8..t*8+7 so that
// kernel B's B-frag(ks, tn) for Q@S is a contiguous 16B load per lane.
__global__ __launch_bounds__(512, 2) void k_state(
    const float* __restrict__ kin, const float* __restrict__ vin,
    short* __restrict__ ws) {
  const int blk = blockIdx.x;
  const int bh  = blk & 63;              // same-bh blocks share blk%8 -> XCD
  const int dsl = blk >> 6;
  const int ds0 = dsl * DCA;
  const float* kb = kin + (size_t)bh * SEQ * DIM;
  const float* vb = vin + (size_t)bh * SEQ * DIM;

  __shared__ short Kt[128][136];   // K^T: Kt[d'][j]
  __shared__ short Vt[DCA][136];   // V^T slice: Vt[d - ds0][j]
  __shared__ short Ss[DCA][136];   // S^T slice bf16: Ss[d - ds0][d']

  const int tid  = threadIdx.x;
  const int wave = tid >> 6;
  const int lane = tid & 63;
  const int q4   = lane >> 4;
  const int l16  = lane & 15;
  const int j    = tid & 127;      // staging row
  const int dhi  = tid >> 7;       // 0..3

  floatx4 acc[2];                  // S^T[d = mt*16+q4*4+r][d' = 16*wave+l16]
#pragma unroll
  for (int mt = 0; mt < 2; ++mt)
#pragma unroll
    for (int r = 0; r < 4; ++r) acc[mt][r] = 0.f;

  float4 kreg[4][2], vreg[2];
  auto load_c = [&](int c) {
    const float* krow = kb + (size_t)(c * CHUNK + j) * DIM + dhi * 8;
#pragma unroll
    for (int it = 0; it < 4; ++it) {
      kreg[it][0] = *(const float4*)(krow + it * 32);
      kreg[it][1] = *(const float4*)(krow + it * 32 + 4);
    }
    const float* vrow = vb + (size_t)(c * CHUNK + j) * DIM + ds0 + dhi * 8;
    vreg[0] = *(const float4*)(vrow);
    vreg[1] = *(const float4*)(vrow + 4);
  };
  load_c(0);

  for (int c = 0; c < NCHUNK; ++c) {
    __syncthreads();   // prev iteration's Kt/Vt/Ss consumers done

    // ---- stage K^T (scalar transposed writes: lanes vary j -> row-consec)
#pragma unroll
    for (int it = 0; it < 4; ++it) {
      const int d0 = it * 32 + dhi * 8;
      Kt[d0 + 0][j] = f2bf(kreg[it][0].x);
      Kt[d0 + 1][j] = f2bf(kreg[it][0].y);
      Kt[d0 + 2][j] = f2bf(kreg[it][0].z);
      Kt[d0 + 3][j] = f2bf(kreg[it][0].w);
      Kt[d0 + 4][j] = f2bf(kreg[it][1].x);
      Kt[d0 + 5][j] = f2bf(kreg[it][1].y);
      Kt[d0 + 6][j] = f2bf(kreg[it][1].z);
      Kt[d0 + 7][j] = f2bf(kreg[it][1].w);
    }
    // ---- stage V^T slice
    {
      const int d0 = dhi * 8;
      Vt[d0 + 0][j] = f2bf(vreg[0].x);
      Vt[d0 + 1][j] = f2bf(vreg[0].y);
      Vt[d0 + 2][j] = f2bf(vreg[0].z);
      Vt[d0 + 3][j] = f2bf(vreg[0].w);
      Vt[d0 + 4][j] = f2bf(vreg[1].x);
      Vt[d0 + 5][j] = f2bf(vreg[1].y);
      Vt[d0 + 6][j] = f2bf(vreg[1].z);
      Vt[d0 + 7][j] = f2bf(vreg[1].w);
    }
    // ---- dump exclusive (pre-chunk) state to Ss
#pragma unroll
    for (int mt = 0; mt < 2; ++mt)
#pragma unroll
      for (int r = 0; r < 4; ++r)
        Ss[mt * 16 + q4 * 4 + r][wave * 16 + l16] = f2bf(acc[mt][r]);

    __syncthreads();

    if (c + 1 < NCHUNK) load_c(c + 1);   // prefetch in flight during compute

    // ---- copy Ss -> ws in B-fragment layout (vector 16B read + store)
    {
      const int ks2 = tid >> 7, tnl = (tid >> 6) & 1;
      const int q42 = (tid >> 4) & 3, l162 = tid & 15;
      const short8 sv = *(const short8*)&Ss[tnl * 16 + l162][ks2 * 32 + q42 * 8];
      *(short8*)&ws[((size_t)((bh * 16 + c) * 4 + dsl)) * 4096 + (size_t)tid * 8] = sv;
    }

    // ---- accumulate chunk c: S^T += V^T K (A = Vt rows, B = Kt rows)
#pragma unroll
    for (int ks = 0; ks < 4; ++ks) {
      const short8 bk = *(const short8*)&Kt[wave * 16 + l16][ks * 32 + q4 * 8];
#pragma unroll
      for (int mt = 0; mt < 2; ++mt) {
        const short8 av = *(const short8*)&Vt[mt * 16 + l16][ks * 32 + q4 * 8];
        acc[mt] = MFMA(av, bk, acc[mt]);
      }
    }
  }
}

// ---------------------------------------------------------------------------
// Kernel B: one block per (bh, chunk).  Wave w owns i-tile w (16 rows), full
// D=128 output (8 n-tiles).  Single barrier; Ps written/read by same wave.
__global__ __launch_bounds__(512, 2) void k_out(
    const float* __restrict__ qin, const float* __restrict__ kin,
    const float* __restrict__ vin, const short* __restrict__ ws,
    float* __restrict__ out) {
  const int blk = blockIdx.x;
  const int bh  = blk & 63;              // same-bh blocks share blk%8 -> XCD
  const int c   = blk >> 6;
  const size_t base = (size_t)bh * SEQ * DIM + (size_t)c * CHUNK * DIM;
  const float* qc = qin + base;
  const float* kc = kin + base;
  const float* vc = vin + base;
  float* oc = out + base;

  __shared__ short Klds[128][136];  // K chunk bf16 row-major
  __shared__ short Vt[128][136];    // V^T: Vt[d][j]
  __shared__ short Ps[128][136];    // masked scores: Ps[i_loc][j]
  __shared__ short Sb[16384];       // S_pre frag blob (bf16, frag layout)

  const int tid  = threadIdx.x;
  const int wave = tid >> 6;
  const int lane = tid & 63;
  const int q4   = lane >> 4;
  const int l16  = lane & 15;
  const int j    = tid & 127;
  const int dhi  = tid >> 7;

  // ---- Q fragments straight to registers
  const float* qrow = qc + (size_t)(wave * 16 + l16) * DIM + q4 * 8;
  short8 aq[4];
#pragma unroll
  for (int ks = 0; ks < 4; ++ks)
    aq[ks] = pack8(*(const float4*)(qrow + ks * 32),
                   *(const float4*)(qrow + ks * 32 + 4));

  // ---- stage K row-major bf16 (vector b128 stores)
#pragma unroll
  for (int it = 0; it < 4; ++it) {
    const int e = it * 4096 + tid * 8;
    *(short8*)&Klds[e >> 7][e & 127] =
        pack8(*(const float4*)(kc + e), *(const float4*)(kc + e + 4));
  }
  // ---- stage V^T (scalar transposed writes, row-consecutive lanes)
#pragma unroll
  for (int it = 0; it < 4; ++it) {
    const int d0 = it * 32 + dhi * 8;
    const float* vrow = vc + (size_t)j * DIM + d0;
    const float4 a = *(const float4*)vrow;
    const float4 b = *(const float4*)(vrow + 4);
    Vt[d0 + 0][j] = f2bf(a.x); Vt[d0 + 1][j] = f2bf(a.y);
    Vt[d0 + 2][j] = f2bf(a.z); Vt[d0 + 3][j] = f2bf(a.w);
    Vt[d0 + 4][j] = f2bf(b.x); Vt[d0 + 5][j] = f2bf(b.y);
    Vt[d0 + 6][j] = f2bf(b.z); Vt[d0 + 7][j] = f2bf(b.w);
  }
  // ---- stage S_pre frag blob (linear vector copy)
  if (c > 0) {
    const short* sp = ws + (size_t)(bh * 16 + c) * 16384;
#pragma unroll
    for (int it = 0; it < 4; ++it) {
      const int off = it * 4096 + tid * 8;
      *(short8*)&Sb[off] = *(const short8*)&sp[off];
    }
  }
  __syncthreads();

  floatx4 oacc[8];
#pragma unroll
  for (int tn = 0; tn < 8; ++tn)
#pragma unroll
    for (int r = 0; r < 4; ++r) oacc[tn][r] = 0.f;

  // ---- inter-chunk part: O += Q @ S_pre (B-frags direct from blob)
  if (c > 0) {
#pragma unroll
    for (int ks = 0; ks < 4; ++ks)
#pragma unroll
      for (int tn = 0; tn < 8; ++tn) {
        const short8 bs = *(const short8*)
            &Sb[(tn >> 1) * 4096 + ks * 1024 + (tn & 1) * 512 + lane * 8];
        oacc[tn] = MFMA(aq[ks], bs, oacc[tn]);
      }
  }

  // ---- intra-chunk causal scores for i-tile `wave`
  for (int tj = 0; tj <= wave; ++tj) {
    floatx4 sacc;
#pragma unroll
    for (int r = 0; r < 4; ++r) sacc[r] = 0.f;
#pragma unroll
    for (int ks = 0; ks < 4; ++ks) {
      const short8 bk = *(const short8*)&Klds[tj * 16 + l16][ks * 32 + q4 * 8];
      sacc = MFMA(aq[ks], bk, sacc);
    }
#pragma unroll
    for (int r = 0; r < 4; ++r) {
      float val = sacc[r];
      if (tj == wave && l16 > q4 * 4 + r) val = 0.f;   // strict-upper mask
      Ps[wave * 16 + q4 * 4 + r][tj * 16 + l16] = f2bf(val);
    }
  }
  if ((wave & 1) == 0) {   // even wave: zero tile wave+1 (PV k-step pad)
#pragma unroll
    for (int r = 0; r < 4; ++r)
      Ps[wave * 16 + q4 * 4 + r][(wave + 1) * 16 + l16] = 0;
  }

  // ---- PV: same-wave Ps rows (no barrier needed)
  const int kst = (wave + 2) >> 1;
  for (int t = 0; t < kst; ++t) {
    const short8 ap = *(const short8*)&Ps[wave * 16 + l16][t * 32 + q4 * 8];
#pragma unroll
    for (int tn = 0; tn < 8; ++tn) {
      const short8 bv = *(const short8*)&Vt[tn * 16 + l16][t * 32 + q4 * 8];
      oacc[tn] = MFMA(ap, bv, oacc[tn]);
    }
  }

  // ---- write out tile (fp32)
#pragma unroll
  for (int tn = 0; tn < 8; ++tn)
#pragma unroll
    for (int r = 0; r < 4; ++r)
      oc[(size_t)(wave * 16 + q4 * 4 + r) * DIM + tn * 16 + l16] = oacc[tn][r];
}

// ---------------------------------------------------------------------------
extern "C" void kernel_launch(void* const* d_in, const int* in_sizes, int n_in,
                              void* d_out, int out_size, void* d_ws, size_t ws_size,
                              hipStream_t stream) {
  const float* q = (const float*)d_in[0];
  const float* k = (const float*)d_in[1];
  const float* v = (const float*)d_in[2];
  float* out = (float*)d_out;
  (void)in_sizes; (void)n_in; (void)out_size; (void)ws_size;
  // requires ws_size >= 64*16*16384*2 = 32 MiB
  short* ws = (short*)d_ws;

  hipLaunchKernelGGL(k_state, dim3(NBH * DSLA), dim3(512), 0, stream, k, v, ws);
  hipLaunchKernelGGL(k_out, dim3(NBH * NCHUNK), dim3(512), 0, stream,
                     q, k, v, ws, out);
}

// Round 3
// 271.087 us; speedup vs baseline: 1.0513x; 1.0513x over previous
//
#include <hip/hip_runtime.h>
#include <stdint.h>

// Two-phase fused causal linear attention (B=4 H=16 T=2048 D=128, fp32 io):
//   out[b,h,i,:] = sum_{j<=i} (q_i . k_j) * v_j
// Phase A (k_state): exclusive prefix states via serial 16-chunk scan,
//   grid 256 = 64 bh x 4 d-slices.  K/V staged fp32 by global_load_lds
//   (async, no VGPR round-trip -- the v1 register prefetch was serialized
//   by the compiler: VGPR_Count=40 proved the 40-reg prefetch was dead).
//   Granule XOR-swizzle applied on the GLOBAL source and repeated on the
//   LDS read so the convert pass's per-lane-row b128 reads run at the
//   LDS data-width floor (rows start at bank 0; XOR spreads the 8 16B
//   slot-groups across consecutive lanes).
// Phase B (k_out): 1024 parallel blocks (bh, chunk), 2 blocks/CU:
//   LDS cut 137->70KB by (a) scores held in regs, P written into the K
//   buffer after a barrier, (b) Q@S B-frags read directly from ws (L2).
#define SEQ    2048
#define DIM    128
#define CHUNK  128
#define NCHUNK 16
#define NBH    64
#define DSLA   4
#define DCA    32           // DIM / DSLA

typedef __attribute__((ext_vector_type(8))) short short8;   // 8 bf16
typedef __attribute__((ext_vector_type(4))) float floatx4;  // MFMA acc

#define MFMA(a, b, c) __builtin_amdgcn_mfma_f32_16x16x32_bf16((a), (b), (c), 0, 0, 0)

__device__ __forceinline__ short f2bf(float f) {
  union { float f; uint32_t u; } x; x.f = f;
  uint32_t r = x.u + 0x7fffu + ((x.u >> 16) & 1u);   // RNE
  return (short)(r >> 16);
}
__device__ __forceinline__ short8 pack8(const float4 a, const float4 b) {
  short8 s;
  s[0] = f2bf(a.x); s[1] = f2bf(a.y); s[2] = f2bf(a.z); s[3] = f2bf(a.w);
  s[4] = f2bf(b.x); s[5] = f2bf(b.y); s[6] = f2bf(b.z); s[7] = f2bf(b.w);
  return s;
}
// async 16B HBM->LDS; dest is wave-uniform base + lane*16 (our per-lane
// pointer is exactly that since g = const + lane).
__device__ __forceinline__ void gload16(const float* g, float* l) {
  __builtin_amdgcn_global_load_lds(
      (const __attribute__((address_space(1))) void*)g,
      (__attribute__((address_space(3))) void*)l, 16, 0, 0);
}

// ---------------------------------------------------------------------------
// Kernel A: exclusive prefix of S_c = K_c^T V_c (slice of 32 d-columns).
// ws record layout unchanged from the verified v1 (B reads it verbatim).
__global__ __launch_bounds__(512, 2) void k_state(
    const float* __restrict__ kin, const float* __restrict__ vin,
    short* __restrict__ ws) {
  const int blk = blockIdx.x;
  const int bh  = blk & 63;              // same-bh blocks share blk%8 -> XCD
  const int dsl = blk >> 6;
  const int ds0 = dsl * DCA;
  const float* kb = kin + (size_t)bh * SEQ * DIM;
  const float* vb = vin + (size_t)bh * SEQ * DIM;

  __shared__ __align__(16) float Kf[128 * 128];  // fp32 landing (gload_lds)
  __shared__ __align__(16) float Vf[128 * 32];   // fp32 landing (gload_lds)
  __shared__ short Kt[128][136];   // K^T bf16: Kt[d'][j]
  __shared__ short Vt[DCA][136];   // V^T slice bf16: Vt[d_loc][j]
  __shared__ short Ss[DCA][136];   // exclusive state bf16: Ss[d_loc][d']

  const int tid  = threadIdx.x;
  const int wave = tid >> 6;
  const int lane = tid & 63;
  const int q4   = lane >> 4;
  const int l16  = lane & 15;
  const int j    = tid & 127;      // convert-pass row
  const int dhi  = tid >> 7;       // 0..3

  floatx4 acc[2];                  // S^T[d = mt*16+q4*4+r][d' = 16*wave+l16]
#pragma unroll
  for (int mt = 0; mt < 2; ++mt)
#pragma unroll
    for (int r = 0; r < 4; ++r) acc[mt][r] = 0.f;

  // issue async landing of chunk c.  Kf granule (row jr, phys q) receives
  // global granule (jr, q ^ (jr&7)) -- involutive swizzle, undone on read.
  auto stage_async = [&](int c) {
    const float* kc = kb + (size_t)c * CHUNK * DIM;
#pragma unroll
    for (int i = 0; i < 8; ++i) {
      const int g  = i * 512 + tid;        // uniform base + lane
      const int jr = g >> 5, pq = g & 31;
      gload16(kc + jr * DIM + ((pq ^ (jr & 7)) << 2), &Kf[g * 4]);
    }
    const float* vc = vb + (size_t)c * CHUNK * DIM + ds0;
#pragma unroll
    for (int i = 0; i < 2; ++i) {
      const int g  = i * 512 + tid;
      const int jr = g >> 3, pq = g & 7;
      gload16(vc + (size_t)jr * DIM + ((pq ^ (jr & 7)) << 2), &Vf[g * 4]);
    }
  };

  stage_async(0);

  for (int c = 0; c < NCHUNK; ++c) {
    __syncthreads();   // drains vmcnt: chunk-c landing done; prev consumers done

    // ---- convert pass: Kf[j][*] -> Kt[*][j]  (swizzled b128 reads) ----
#pragma unroll
    for (int it = 0; it < 8; ++it) {
      const int q = dhi * 8 + it;
      const float4 x = *(const float4*)&Kf[(j << 7) + ((q ^ (j & 7)) << 2)];
      const int d0 = q * 4;
      Kt[d0 + 0][j] = f2bf(x.x);
      Kt[d0 + 1][j] = f2bf(x.y);
      Kt[d0 + 2][j] = f2bf(x.z);
      Kt[d0 + 3][j] = f2bf(x.w);
    }
#pragma unroll
    for (int s = 0; s < 2; ++s) {
      const int q = dhi * 2 + s;
      const float4 x = *(const float4*)&Vf[(j << 5) + ((q ^ (j & 7)) << 2)];
      const int d0 = q * 4;
      Vt[d0 + 0][j] = f2bf(x.x);
      Vt[d0 + 1][j] = f2bf(x.y);
      Vt[d0 + 2][j] = f2bf(x.z);
      Vt[d0 + 3][j] = f2bf(x.w);
    }
    // ---- dump exclusive (pre-chunk) state to Ss ----
#pragma unroll
    for (int mt = 0; mt < 2; ++mt)
#pragma unroll
      for (int r = 0; r < 4; ++r)
        Ss[mt * 16 + q4 * 4 + r][wave * 16 + l16] = f2bf(acc[mt][r]);

    __syncthreads();   // Kf/Vf reads done; Kt/Vt/Ss visible

    if (c + 1 < NCHUNK) stage_async(c + 1);   // flies during compute

    // ---- copy Ss -> ws in B-fragment layout (unchanged, verified) ----
    {
      const int ks2 = tid >> 7, tnl = (tid >> 6) & 1;
      const int q42 = (tid >> 4) & 3, l162 = tid & 15;
      const short8 sv = *(const short8*)&Ss[tnl * 16 + l162][ks2 * 32 + q42 * 8];
      *(short8*)&ws[((size_t)((bh * 16 + c) * 4 + dsl)) * 4096 + (size_t)tid * 8] = sv;
    }

    // ---- accumulate chunk c: S^T += V^T K (unchanged, verified) ----
#pragma unroll
    for (int ks = 0; ks < 4; ++ks) {
      const short8 bk = *(const short8*)&Kt[wave * 16 + l16][ks * 32 + q4 * 8];
#pragma unroll
      for (int mt = 0; mt < 2; ++mt) {
        const short8 av = *(const short8*)&Vt[mt * 16 + l16][ks * 32 + q4 * 8];
        acc[mt] = MFMA(av, bk, acc[mt]);
      }
    }
  }
}

// ---------------------------------------------------------------------------
// Kernel B: one block per (bh, chunk).  LDS 70KB -> 2 blocks/CU.
// KP doubles as K (row-major bf16) for scores, then (after barrier) as the
// masked-P buffer for PV.  Q@S B-frags come straight from ws (L2-local:
// same-bh blocks of A and B share blk&7 -> same XCD).
__global__ __launch_bounds__(512, 4) void k_out(
    const float* __restrict__ qin, const float* __restrict__ kin,
    const float* __restrict__ vin, const short* __restrict__ ws,
    float* __restrict__ out) {
  const int blk = blockIdx.x;
  const int bh  = blk & 63;              // same-bh blocks share blk%8 -> XCD
  const int c   = blk >> 6;
  const size_t base = (size_t)bh * SEQ * DIM + (size_t)c * CHUNK * DIM;
  const float* qc = qin + base;
  const float* kc = kin + base;
  const float* vc = vin + base;
  float* oc = out + base;

  __shared__ short KP[128][136];    // K chunk bf16; later masked P
  __shared__ short Vt[128][136];    // V^T: Vt[d][j]

  const int tid  = threadIdx.x;
  const int wave = tid >> 6;
  const int lane = tid & 63;
  const int q4   = lane >> 4;
  const int l16  = lane & 15;
  const int j    = tid & 127;
  const int dhi  = tid >> 7;

  // ---- Q fragments straight to registers
  const float* qrow = qc + (size_t)(wave * 16 + l16) * DIM + q4 * 8;
  short8 aq[4];
#pragma unroll
  for (int ks = 0; ks < 4; ++ks)
    aq[ks] = pack8(*(const float4*)(qrow + ks * 32),
                   *(const float4*)(qrow + ks * 32 + 4));

  // ---- stage K row-major bf16 (vector b128 stores)
#pragma unroll
  for (int it = 0; it < 4; ++it) {
    const int e = it * 4096 + tid * 8;
    *(short8*)&KP[e >> 7][e & 127] =
        pack8(*(const float4*)(kc + e), *(const float4*)(kc + e + 4));
  }
  // ---- stage V^T (scalar transposed writes, row-consecutive lanes)
#pragma unroll
  for (int it = 0; it < 4; ++it) {
    const int d0 = it * 32 + dhi * 8;
    const float* vrow = vc + (size_t)j * DIM + d0;
    const float4 a = *(const float4*)vrow;
    const float4 b = *(const float4*)(vrow + 4);
    Vt[d0 + 0][j] = f2bf(a.x); Vt[d0 + 1][j] = f2bf(a.y);
    Vt[d0 + 2][j] = f2bf(a.z); Vt[d0 + 3][j] = f2bf(a.w);
    Vt[d0 + 4][j] = f2bf(b.x); Vt[d0 + 5][j] = f2bf(b.y);
    Vt[d0 + 6][j] = f2bf(b.z); Vt[d0 + 7][j] = f2bf(b.w);
  }
  __syncthreads();

  floatx4 oacc[8];
#pragma unroll
  for (int tn = 0; tn < 8; ++tn)
#pragma unroll
    for (int r = 0; r < 4; ++r) oacc[tn][r] = 0.f;

  // ---- inter-chunk part: O += Q @ S_pre, B-frags direct from global ws
  if (c > 0) {
    const short* sp = ws + (size_t)(bh * 16 + c) * 16384;
#pragma unroll
    for (int ks = 0; ks < 4; ++ks)
#pragma unroll
      for (int tg = 0; tg < 2; ++tg) {
        short8 bs[4];
#pragma unroll
        for (int t = 0; t < 4; ++t) {
          const int tn = tg * 4 + t;
          bs[t] = *(const short8*)
              &sp[(tn >> 1) * 4096 + ks * 1024 + (tn & 1) * 512 + lane * 8];
        }
#pragma unroll
        for (int t = 0; t < 4; ++t)
          oacc[tg * 4 + t] = MFMA(aq[ks], bs[t], oacc[tg * 4 + t]);
      }
  }

  // ---- intra-chunk causal scores for i-tile `wave`, held in registers
  floatx4 sacc[8];
#pragma unroll
  for (int tj = 0; tj < 8; ++tj) {
    if (tj > wave) continue;           // wave-uniform; tj static (rule #20 ok)
#pragma unroll
    for (int r = 0; r < 4; ++r) sacc[tj][r] = 0.f;
#pragma unroll
    for (int ks = 0; ks < 4; ++ks) {
      const short8 bk = *(const short8*)&KP[tj * 16 + l16][ks * 32 + q4 * 8];
      sacc[tj] = MFMA(aq[ks], bk, sacc[tj]);
    }
  }
  __syncthreads();   // all K reads done; KP becomes the P buffer

  // ---- masked P into KP (each wave writes only its own 16 rows)
#pragma unroll
  for (int tj = 0; tj < 8; ++tj) {
    if (tj > wave) continue;
#pragma unroll
    for (int r = 0; r < 4; ++r) {
      float val = sacc[tj][r];
      if (tj == wave && l16 > q4 * 4 + r) val = 0.f;   // strict-upper mask
      KP[wave * 16 + q4 * 4 + r][tj * 16 + l16] = f2bf(val);
    }
  }
  if ((wave & 1) == 0) {   // even wave: zero tile wave+1 (PV k-step pad)
#pragma unroll
    for (int r = 0; r < 4; ++r)
      KP[wave * 16 + q4 * 4 + r][(wave + 1) * 16 + l16] = 0;
  }

  // ---- PV: same-wave P rows (no barrier needed)
  const int kst = (wave + 2) >> 1;
  for (int t = 0; t < kst; ++t) {
    const short8 ap = *(const short8*)&KP[wave * 16 + l16][t * 32 + q4 * 8];
#pragma unroll
    for (int tn = 0; tn < 8; ++tn) {
      const short8 bv = *(const short8*)&Vt[tn * 16 + l16][t * 32 + q4 * 8];
      oacc[tn] = MFMA(ap, bv, oacc[tn]);
    }
  }

  // ---- write out tile (fp32)
#pragma unroll
  for (int tn = 0; tn < 8; ++tn)
#pragma unroll
    for (int r = 0; r < 4; ++r)
      oc[(size_t)(wave * 16 + q4 * 4 + r) * DIM + tn * 16 + l16] = oacc[tn][r];
}

// ---------------------------------------------------------------------------
extern "C" void kernel_launch(void* const* d_in, const int* in_sizes, int n_in,
                              void* d_out, int out_size, void* d_ws, size_t ws_size,
                              hipStream_t stream) {
  const float* q = (const float*)d_in[0];
  const float* k = (const float*)d_in[1];
  const float* v = (const float*)d_in[2];
  float* out = (float*)d_out;
  (void)in_sizes; (void)n_in; (void)out_size; (void)ws_size;
  // requires ws_size >= 64*16*16384*2 = 32 MiB
  short* ws = (short*)d_ws;

  hipLaunchKernelGGL(k_state, dim3(NBH * DSLA), dim3(512), 0, stream, k, v, ws);
  hipLaunchKernelGGL(k_out, dim3(NBH * NCHUNK), dim3(512), 0, stream,
                     q, k, v, ws, out);
}